// Round 21
// baseline (46.603 us; speedup 1.0000x reference)
//
#include <hip/hip_runtime.h>

#define NG 48
#define NT 6                    // 4 A tiles per axis (8 cells)
#define NTILES (NT * NT * NT)   // 216
#define CHUNK 512               // atoms per bin block
#define NCHUNK 32               // 16384 / 512
#define SUBCAP 96               // per-(tile,chunk) capacity; lambda ~32
#define NSEG 8                  // gather segments = chunk groups of 4
#define CPSEG (NCHUNK / NSEG)   // 4 chunks per segment
// ws layout:
//   [0,      82944)   int cntc[3*216][NCHUNK]
//   [131072, +3.98M)  u16 lists[3*216][NCHUNK][SUBCAP]
//   [8MiB,   +10.6M)  float copies[3*216][NSEG][512]
#define LISTS_OFF  131072
#define COPIES_OFF (8u << 20)

__device__ __forceinline__ float type_r(int type) {
    return (type == 0) ? 1.7f : ((type == 1) ? 1.55f : 1.52f);
}

// Phase 1 (proven since R13): one block per (512-atom chunk, type). LDS
// histogram -> chunk-private sub-lists, plain stores, no global atomics.
__global__ __launch_bounds__(512) void bin_kernel(
    const float* __restrict__ vC, const float* __restrict__ vN,
    const float* __restrict__ vO, int* __restrict__ cntc,
    unsigned short* __restrict__ lists, int natoms)
{
    const int type  = blockIdx.y;
    const int chunk = blockIdx.x;
    const float r = type_r(type);
    const float b = 1.5f * r + 1e-3f;
    const float* __restrict__ vecs = (type == 0) ? vC : ((type == 1) ? vN : vO);
    const int tid  = threadIdx.x;
    const int atom = chunk * CHUNK + tid;

    __shared__ int lfill[NTILES];
    if (tid < NTILES) lfill[tid] = 0;
    __syncthreads();

    int x0 = 1, x1 = 0, y0 = 1, y1 = 0, z0 = 1, z1 = 0;
    if (atom < natoms) {
        const float vx = vecs[3 * atom + 0] + 23.5f;  // vec = raw + 24 - 0.5
        const float vy = vecs[3 * atom + 1] + 23.5f;
        const float vz = vecs[3 * atom + 2] + 23.5f;
        // tile t intersects the 1.5r halo iff 4t > v - b - 3.5 and 4t < v + b
        x0 = max(0,      (int)floorf((vx - 3.5f - b) * 0.25f) + 1);
        x1 = min(NT - 1, (int)ceilf ((vx + b)        * 0.25f) - 1);
        y0 = max(0,      (int)floorf((vy - 3.5f - b) * 0.25f) + 1);
        y1 = min(NT - 1, (int)ceilf ((vy + b)        * 0.25f) - 1);
        z0 = max(0,      (int)floorf((vz - 3.5f - b) * 0.25f) + 1);
        z1 = min(NT - 1, (int)ceilf ((vz + b)        * 0.25f) - 1);
    }
    const bool has = (x0 <= x1) & (y0 <= y1) & (z0 <= z1);

    if (has)
        for (int tx = x0; tx <= x1; ++tx)
            for (int ty = y0; ty <= y1; ++ty)
                for (int tz = z0; tz <= z1; ++tz) {
                    const int tl = (tx * NT + ty) * NT + tz;
                    const int p  = atomicAdd(&lfill[tl], 1);   // LDS only
                    if (p < SUBCAP)
                        lists[((size_t)(type * NTILES + tl) * NCHUNK + chunk)
                              * SUBCAP + p] = (unsigned short)atom;
                }
    __syncthreads();

    if (tid < NTILES)
        cntc[(type * NTILES + tid) * NCHUNK + chunk] = min(lfill[tid], SUBCAP);
}

// Phase 2: one 128-thread block (2 waves) per (segment, tile, type).
// Prologue: ONE broadcast int4 load of the 4 chunk counts -> register
// prefix -> empty blocks exit in ~600cy with NO barrier (old version: tid0
// did 4 serial dependent loads + full-block barrier, paid even by the 90%
// empty blocks). Eval: R18's proven 4-cell culled body (2 wave-iters per
// staged atom instead of 4).
__global__ __launch_bounds__(128) void gather_seg(
    const float* __restrict__ vC, const float* __restrict__ vN,
    const float* __restrict__ vO, const int* __restrict__ cntc,
    const unsigned short* __restrict__ lists, float* __restrict__ copies)
{
    const int type = blockIdx.y;
    const int s = blockIdx.x / NTILES;        // segment-major spread
    const int t = blockIdx.x - s * NTILES;
    const int lt = type * NTILES + t;
    const int tid = threadIdx.x;              // 0..127

    // ---- register prologue: one broadcast 16B load, no LDS, no barrier ----
    const int4 c4 = *reinterpret_cast<const int4*>(
        &cntc[lt * NCHUNK + s * CPSEG]);      // 16B-aligned
    const int e0 = c4.x;
    const int e1 = e0 + c4.y;
    const int e2 = e1 + c4.z;
    const int total = e2 + c4.w;
    if (total == 0) return;                   // fast exit, no sync needed

    const float r = type_r(type);
    const float* __restrict__ vecs = (type == 0) ? vC : ((type == 1) ? vN : vO);

    const int tx = t / (NT * NT);
    const int ty = (t / NT) % NT;
    const int tz = t % NT;
    const int lx = tid >> 5;                  // 0..3 -> x, x+4
    const int ly = (tid >> 2) & 7;            // 0..7
    const int lz = tid & 3;                   // 0..3 -> z, z+4

    const float b      = 1.5f * r;
    const float r15sq  = b * b;
    const float rr     = r * r;
    const float E2     = 7.3890562f;
    const float c2a    = 4.0f / (E2 * rr);
    const float c2b    = 12.0f / (E2 * r);
    const float c2c    = 9.0f / E2;
    const float n2orr  = -2.0f / rr;

    const float px0 = 0.5f * (float)(tx * 8 + lx);
    const float py  = 0.5f * (float)(ty * 8 + ly);
    const float pz0 = 0.5f * (float)(tz * 8 + lz);

    __shared__ float4 sa[128];
    const unsigned short* __restrict__ lbase =
        lists + ((size_t)lt * NCHUNK + s * CPSEG) * SUBCAP;

    float acc00 = 0.0f, acc01 = 0.0f, acc10 = 0.0f, acc11 = 0.0f;

    for (int base = 0; base < total; base += 128) {
        const int m = min(128, total - base);
        if (base) __syncthreads();            // protect sa[] reuse
        if (tid < m) {
            const int g = base + tid;
            int c; int off;
            if (g < e1) { c = (g < e0) ? 0 : 1; off = (g < e0) ? 0 : e0; }
            else        { c = (g < e2) ? 2 : 3; off = (g < e2) ? e1 : e2; }
            const int idx = (int)lbase[(size_t)c * SUBCAP + (g - off)];
            sa[tid] = make_float4(vecs[3 * idx + 0] + 23.5f,
                                  vecs[3 * idx + 1] + 23.5f,
                                  vecs[3 * idx + 2] + 23.5f, 0.0f);
        }
        __syncthreads();

        for (int j = 0; j < m; ++j) {
            const float4 a = sa[j];           // one b128 LDS broadcast
            const float dy  = a.y - py;
            const float sy  = dy * dy;
            const float dz0 = a.z - pz0, dz1 = dz0 - 2.0f;
            const float sz0 = fmaf(dz0, dz0, sy), sz1 = fmaf(dz1, dz1, sy);
            const float dx0 = a.x - px0, dx1 = dx0 - 2.0f;
            const float xx0 = dx0 * dx0, xx1 = dx1 * dx1;
            const float d200 = xx0 + sz0, d201 = xx0 + sz1;
            const float d210 = xx1 + sz0, d211 = xx1 + sz1;
            const bool h00 = d200 < r15sq, h01 = d201 < r15sq;
            const bool h10 = d210 < r15sq, h11 = d211 < r15sq;
            if (__ballot(h00 | h01 | h10 | h11) == 0ull) continue;  // cull
            if (h00) { const float d = sqrtf(d200);
                acc00 += (d < r) ? __expf(n2orr * d200)
                                 : fmaf(c2a, d200, fmaf(-c2b, d, c2c)); }
            if (h01) { const float d = sqrtf(d201);
                acc01 += (d < r) ? __expf(n2orr * d201)
                                 : fmaf(c2a, d201, fmaf(-c2b, d, c2c)); }
            if (h10) { const float d = sqrtf(d210);
                acc10 += (d < r) ? __expf(n2orr * d210)
                                 : fmaf(c2a, d210, fmaf(-c2b, d, c2c)); }
            if (h11) { const float d = sqrtf(d211);
                acc11 += (d < r) ? __expf(n2orr * d211)
                                 : fmaf(c2a, d211, fmaf(-c2b, d, c2c)); }
        }
    }

    // store: local cell = ((X*8)+Y)*8+Z, X=lx(+4), Y=ly, Z=lz(+4)
    float* __restrict__ cp = copies + ((size_t)lt * NSEG + s) * 512;
    cp[((lx      * 8) + ly) * 8 + lz]      = acc00;
    cp[((lx      * 8) + ly) * 8 + lz + 4]  = acc01;
    cp[(((lx + 4) * 8) + ly) * 8 + lz]     = acc10;
    cp[(((lx + 4) * 8) + ly) * 8 + lz + 4] = acc11;
}

// Phase 3 (proven): one block per (tile,type). Sum segments with activity
// (derived from chunk counts) in fixed order; write 512 cells exactly once.
__global__ __launch_bounds__(256) void reduce_kernel(
    const int* __restrict__ cntc, const float* __restrict__ copies,
    float* __restrict__ out)
{
    const int type = blockIdx.y;
    const int t = blockIdx.x;
    const int lt = type * NTILES + t;
    const int tid = threadIdx.x;

    __shared__ int segact[NSEG];
    if (tid < NSEG) {
        int acc = 0;
        #pragma unroll
        for (int c = 0; c < CPSEG; ++c)
            acc += cntc[lt * NCHUNK + tid * CPSEG + c];
        segact[tid] = acc;
    }
    __syncthreads();

    const float* __restrict__ cp = copies + ((size_t)lt * NSEG) * 512;
    float o0 = 0.0f, o1 = 0.0f;
    #pragma unroll
    for (int ss = 0; ss < NSEG; ++ss) {
        if (segact[ss] > 0) {
            o0 += cp[(size_t)ss * 512 + tid];        // cell tid
            o1 += cp[(size_t)ss * 512 + 256 + tid];  // cell tid+256
        }
    }

    const int tx = t / (NT * NT);
    const int ty = (t / NT) % NT;
    const int tz = t % NT;
    const int lx = tid >> 6;
    const int ly = (tid >> 3) & 7;
    const int lz = tid & 7;
    const int X0 = tx * 8 + lx;
    const int Y  = ty * 8 + ly;
    const int Z  = tz * 8 + lz;
    float* __restrict__ o = out + (size_t)type * NG * NG * NG;
    o[((X0      * NG) + Y) * NG + Z] = o0;
    o[(((X0 + 4) * NG) + Y) * NG + Z] = o1;
}

extern "C" void kernel_launch(void* const* d_in, const int* in_sizes, int n_in,
                              void* d_out, int out_size, void* d_ws, size_t ws_size,
                              hipStream_t stream) {
    const float* vC = (const float*)d_in[0];
    const float* vN = (const float*)d_in[1];
    const float* vO = (const float*)d_in[2];
    float* out = (float*)d_out;

    int* cntc = (int*)d_ws;
    unsigned short* lists = (unsigned short*)((char*)d_ws + LISTS_OFF);
    float* copies = (float*)((char*)d_ws + COPIES_OFF);

    const int natoms = in_sizes[0] / 3;               // 16384
    const int nchunk = (natoms + CHUNK - 1) / CHUNK;  // 32 == NCHUNK

    dim3 bgrid(nchunk, 3, 1);
    bin_kernel<<<bgrid, CHUNK, 0, stream>>>(vC, vN, vO, cntc, lists, natoms);

    dim3 ggrid(NTILES * NSEG, 3, 1);
    gather_seg<<<ggrid, 128, 0, stream>>>(vC, vN, vO, cntc, lists, copies);

    dim3 rgrid(NTILES, 3, 1);
    reduce_kernel<<<rgrid, 256, 0, stream>>>(cntc, copies, out);
}